// Round 14
// baseline (3178.150 us; speedup 1.0000x reference)
//
#include <hip/hip_runtime.h>
#include <hip/hip_bf16.h>
#include <cstdint>

// Problem constants (fixed by the reference)
#define NB 4
#define NH 128
#define NW 128
#define NC 256
#define NFF 1024
#define NE 4
#define NPATCH 4096   // B * 32 * 32
#define NPAIR 16      // ordered expert pairs (i1*4+i2), 12 valid
#define PPB 4         // patches per ffn block
#define BM 64         // token rows per ffn block (PPB*16)
#define FFC 128       // FF chunk
#define NCHUNK_TOT 16 // 2 experts x (NFF/FFC)

typedef __attribute__((ext_vector_type(8))) short short8;
typedef __attribute__((ext_vector_type(8))) unsigned short ushort8;
typedef __attribute__((ext_vector_type(16))) float f32x16;

__device__ __forceinline__ unsigned short f2b(float f) {
  union { float f; uint32_t u; } v; v.f = f;
  uint32_t u = v.u + 0x7FFFu + ((v.u >> 16) & 1u);   // RNE
  return (unsigned short)(u >> 16);
}

__device__ __forceinline__ float gelu_f(float v) {
  float u = v * v;
  float t = __builtin_fmaf(u, 0.044715f, 1.0f) * v;
  float e = __builtin_amdgcn_exp2f(t * -2.3022083f);
  return v * __builtin_amdgcn_rcpf(1.0f + e);
}

// barrier that drains LDS ops only (global loads stay in flight)
__device__ __forceinline__ void bar_lgkm() {
  asm volatile("s_waitcnt lgkmcnt(0)" ::: "memory");
  __builtin_amdgcn_s_barrier();
}

// ---------------- weight fp32 -> bf16 (+ cnt zeroing) ----------------
__global__ __launch_bounds__(256) void convert_kernel(
    const float* __restrict__ W1, const float* __restrict__ W2,
    unsigned short* __restrict__ W1b, unsigned short* __restrict__ W2b,
    int* __restrict__ cnt, int n) {
  int i = blockIdx.x * blockDim.x + threadIdx.x;
  if (i < NPAIR) cnt[i] = 0;
  if (i < n) {
    W1b[i] = f2b(W1[i]);
    W2b[i] = f2b(W2[i]);
  }
}

// ---------------- router ----------------
__global__ __launch_bounds__(256) void router_kernel(
    const float* __restrict__ x, const float* __restrict__ Wg,
    int* __restrict__ cnt, int* __restrict__ plist, float2* __restrict__ wlist) {
  int p = blockIdx.x;
  int b = p >> 10, pi = p & 1023;
  int phi = pi >> 5, pwi = pi & 31;
  int c = threadIdx.x;

  const float* base = x + (((size_t)(b * NH + phi * 4) * NW) + pwi * 4) * NC + c;
  float s = 0.f;
#pragma unroll
  for (int i = 0; i < 4; i++)
#pragma unroll
    for (int j = 0; j < 4; j++)
      s += base[(i * NW + j) * NC];
  float mean = s * (1.f / 16.f);

  __shared__ float m_lds[NC];
  __shared__ double logit_lds[NE];
  m_lds[c] = mean;
  __syncthreads();

  int wid = c >> 6, lane = c & 63;
  {
    const float* wg = Wg + wid * NC;
    double acc = 0.0;
#pragma unroll
    for (int q = 0; q < 4; q++)
      acc += (double)m_lds[lane + q * 64] * (double)wg[lane + q * 64];
    for (int off = 32; off; off >>= 1) acc += __shfl_down(acc, off);
    if (lane == 0) logit_lds[wid] = acc;
  }
  __syncthreads();

  if (c == 0) {
    double l[NE], pp[NE];
    double mx = -1e300;
#pragma unroll
    for (int i = 0; i < NE; i++) { l[i] = logit_lds[i]; mx = fmax(mx, l[i]); }
    double sum = 0.0;
#pragma unroll
    for (int i = 0; i < NE; i++) { pp[i] = exp(l[i] - mx); sum += pp[i]; }
#pragma unroll
    for (int i = 0; i < NE; i++) pp[i] /= sum;
    int i1 = 0; double p1 = pp[0];
    for (int i = 1; i < NE; i++) if (pp[i] > p1) { p1 = pp[i]; i1 = i; }
    int i2 = -1; double p2 = -1.0;
    for (int i = 0; i < NE; i++) {
      if (i == i1) continue;
      if (pp[i] > p2) { p2 = pp[i]; i2 = i; }
    }
    double den = p1 + p2 + 1e-9;
    float w1 = (float)(p1 / den), w2 = (float)(p2 / den);
    int pr = i1 * NE + i2;
    int pos = atomicAdd(&cnt[pr], 1);
    plist[pr * NPATCH + pos] = p;
    wlist[pr * NPATCH + pos] = make_float2(w1, w2);
  }
}

// ---------------- worklist: XCD-affine padded slots ----------------
__global__ __launch_bounds__(64) void worklist_kernel(
    const int* __restrict__ cnt, int* __restrict__ wl) {
  int lane = threadIdx.x;
  int cA[8], cB[8], mx = 0;
#pragma unroll
  for (int xc = 0; xc < 8; ++xc) {
    cA[xc] = (cnt[xc] + PPB - 1) / PPB;
    cB[xc] = (cnt[xc + 8] + PPB - 1) / PPB;
    int t = cA[xc] + cB[xc];
    mx = (t > mx) ? t : mx;
  }
  if (lane == 0) wl[0] = 8 * mx;
  int x = lane & 7, sub = lane >> 3;
  int nA = cA[x], tot = cA[x] + cB[x];
  for (int r = sub; r < mx; r += 8) {
    int ent = -1;
    if (r < nA) ent = (x << 12) | (r * PPB);
    else if (r < tot) ent = ((x + 8) << 12) | ((r - nA) * PPB);
    wl[1 + x + 8 * r] = ent;
  }
}

// ---------------- pair-FFN: 32x32x16, fragment-order LDS, NO fences ----------------
// 512 thr / 8 waves, 48 KiB LDS -> 2 blocks/CU (4 waves/SIMD: 2 G1 + 2 G2
// from desynced blocks). Weights load direct global->VGPR (L2-resident);
// the compiler pipelines them freely -- no vmcnt asm anywhere (R13's
// per-K-step fences were the serializer). G1 (waves 0-3): f-tile 32 x both
// t-tiles; GEMM1 swapped (D[f][t]) + GELU + router-scale -> Hf fragment
// pages. G2 (waves 4-7): c-strip 64 x both t-tiles; GEMM2 (D[t][c]) consumes
// chunk j-1; acc (4x f32x16 = 64 VGPR) persists over 16 chunks. All MFMA
// operand LDS reads are lane-linear b128 (conflict-free, verified 3M @R13).
// 2 lgkm-only barriers per chunk.
__global__ __launch_bounds__(512, 4) void ffn_kernel(
    const float* __restrict__ x, const float* __restrict__ b1,
    const float* __restrict__ b2, const unsigned short* __restrict__ W1b,
    const unsigned short* __restrict__ W2b, const int* __restrict__ cnt,
    const int* __restrict__ plist, const float2* __restrict__ wlist,
    const int* __restrict__ wl, float* __restrict__ out) {
  __shared__ unsigned short Xf[2 * 16 * 512];   // 32 KiB: [tt][kk] frag pages
  __shared__ unsigned short Hf[2 * 8 * 512];    // 16 KiB: [tt][kkf] frag pages

  int slotb = blockIdx.x;
  if (slotb >= wl[0]) return;
  int ent = wl[1 + slotb];
  if (ent < 0) return;
  int pr = ent >> 12, pbase = ent & 4095;
  int e1 = pr >> 2, e2 = pr & 3;
  int n = cnt[pr];

  int tid = threadIdx.x, lane = tid & 63, wid = tid >> 6;
  int l31 = lane & 31, lh = lane >> 5;   // 32x32 frag: row/col = l31, k-half = lh

  const int*    pl  = plist + pr * NPATCH + pbase;
  const float2* wlp = wlist + pr * NPATCH + pbase;

  float wvA[PPB], wvB[PPB];
#pragma unroll
  for (int q = 0; q < PPB; q++) {
    if (pbase + q < n) { float2 w = wlp[q]; wvA[q] = w.x; wvB[q] = w.y; }
    else { wvA[q] = 0.f; wvB[q] = 0.f; }
  }

  // ---- gather tokens -> Xf fragment pages (all 512 threads) ----
  {
    int r  = tid >> 3;            // 0..63 token row
    int c0 = (tid & 7) * 32;      // 32 channels per thread
    int pid = (pbase + (r >> 4) < n) ? pl[r >> 4] : -1;
    int t = r & 15;
    int tt = r >> 5, t32 = r & 31;
    if (pid >= 0) {
      int b = pid >> 10, pi = pid & 1023;
      int phi = pi >> 5, pwi = pi & 31;
      const float* src =
          x + (((size_t)(b * NH + phi * 4 + (t >> 2)) * NW) + pwi * 4 + (t & 3)) * NC + c0;
#pragma unroll
      for (int kb = 0; kb < 4; kb++) {
        float4 v0 = *reinterpret_cast<const float4*>(src + kb * 8);
        float4 v1 = *reinterpret_cast<const float4*>(src + kb * 8 + 4);
        ushort8 h;
        h[0] = f2b(v0.x); h[1] = f2b(v0.y); h[2] = f2b(v0.z); h[3] = f2b(v0.w);
        h[4] = f2b(v1.x); h[5] = f2b(v1.y); h[6] = f2b(v1.z); h[7] = f2b(v1.w);
        int k = c0 + kb * 8;
        int uidx = (tt * 16 + (k >> 4)) * 512 + (((k >> 3) & 1) * 32 + t32) * 8;
        *reinterpret_cast<ushort8*>(&Xf[uidx]) = h;
      }
    } else {
      ushort8 h = (ushort8)0;
#pragma unroll
      for (int kb = 0; kb < 4; kb++) {
        int k = c0 + kb * 8;
        int uidx = (tt * 16 + (k >> 4)) * 512 + (((k >> 3) & 1) * 32 + t32) * 8;
        *reinterpret_cast<ushort8*>(&Xf[uidx]) = h;
      }
    }
  }
  bar_lgkm();   // Xf visible

  const unsigned short* W1A = W1b + (size_t)e1 * NFF * NC;
  const unsigned short* W1B = W1b + (size_t)e2 * NFF * NC;
  const unsigned short* W2A = W2b + (size_t)e1 * NC * NFF;
  const unsigned short* W2B = W2b + (size_t)e2 * NC * NFF;

  if (wid < 4) {
    // ================= G1: producer =================
    int wf = wid;
    const float* b1A = b1 + e1 * NFF;
    const float* b1B = b1 + e2 * NFF;

    f32x16 a0, a1;
    ushort4 hreg[8];

#pragma unroll 1
    for (int j = 0; j < NCHUNK_TOT; ++j) {
      int fc = j & 7;
      const unsigned short* W1e = (j < 8) ? W1A : W1B;
      const float* b1e = (j < 8) ? b1A : b1B;
      a0 = (f32x16)0.f; a1 = (f32x16)0.f;

      const unsigned short* wrow = W1e + (size_t)(fc * FFC + wf * 32 + l31) * NC + lh * 8;
#pragma unroll
      for (int kf = 0; kf < 16; ++kf) {
        short8 aW = *reinterpret_cast<const short8*>(wrow + kf * 16);
        short8 bX0 = *reinterpret_cast<const short8*>(&Xf[(0 * 16 + kf) * 512 + lane * 8]);
        short8 bX1 = *reinterpret_cast<const short8*>(&Xf[(1 * 16 + kf) * 512 + lane * 8]);
        __builtin_amdgcn_s_setprio(1);
        a0 = __builtin_amdgcn_mfma_f32_32x32x16_bf16(aW, bX0, a0, 0, 0, 0);
        a1 = __builtin_amdgcn_mfma_f32_32x32x16_bf16(aW, bX1, a1, 0, 0, 0);
        __builtin_amdgcn_s_setprio(0);
      }

      // GELU + router-scale -> hreg. D[f][t]: t = l31 (col=lane), patch
      // selected by l31>>4 within the t-tile (R13-verified).
#pragma unroll
      for (int tt = 0; tt < 2; ++tt) {
        const f32x16& A = (tt == 0) ? a0 : a1;
        float wlo = (j < 8) ? wvA[tt * 2]     : wvB[tt * 2];
        float whi = (j < 8) ? wvA[tt * 2 + 1] : wvB[tt * 2 + 1];
        float w = (l31 >= 16) ? whi : wlo;
#pragma unroll
        for (int q = 0; q < 4; ++q) {
          int qs = q * 8 + lh * 4;                  // f-local base of this reg-quad
          float4 bv = *reinterpret_cast<const float4*>(b1e + fc * FFC + wf * 32 + qs);
          ushort4 hp;
          hp.x = f2b(gelu_f(A[q * 4 + 0] + bv.x) * w);
          hp.y = f2b(gelu_f(A[q * 4 + 1] + bv.y) * w);
          hp.z = f2b(gelu_f(A[q * 4 + 2] + bv.z) * w);
          hp.w = f2b(gelu_f(A[q * 4 + 3] + bv.w) * w);
          hreg[tt * 4 + q] = hp;
        }
      }
      bar_lgkm();   // BAR1: G2 done reading Hf (chunk j-1)
#pragma unroll
      for (int tt = 0; tt < 2; ++tt) {
#pragma unroll
        for (int q = 0; q < 4; ++q) {
          int qs = q * 8 + lh * 4;
          int page = tt * 8 + wf * 2 + (qs >> 4);
          int uidx = page * 512 + ((((qs >> 3) & 1) * 32 + l31)) * 8 + (qs & 4);
          *reinterpret_cast<ushort4*>(&Hf[uidx]) = hreg[tt * 4 + q];
        }
      }
      bar_lgkm();   // BAR2: Hf(j) published
    }
    // G1 exits (barriers: 1 + 32)
  } else {
    // ================= G2: consumer =================
    int wc = wid - 4;

    f32x16 y00 = (f32x16)0.f, y01 = (f32x16)0.f;
    f32x16 y10 = (f32x16)0.f, y11 = (f32x16)0.f;

    // consume chunk jc from Hf (8 K-frags of 16f)
    auto consume = [&](int jc) {
      int fcp = jc & 7;
      const unsigned short* W2e = (jc < 8) ? W2A : W2B;
      const unsigned short* w0 = W2e + (size_t)(wc * 64 + l31) * NFF + fcp * FFC + lh * 8;
      const unsigned short* w1 = W2e + (size_t)(wc * 64 + 32 + l31) * NFF + fcp * FFC + lh * 8;
#pragma unroll
      for (int kkf = 0; kkf < 8; ++kkf) {
        short8 aH0 = *reinterpret_cast<const short8*>(&Hf[(0 * 8 + kkf) * 512 + lane * 8]);
        short8 aH1 = *reinterpret_cast<const short8*>(&Hf[(1 * 8 + kkf) * 512 + lane * 8]);
        short8 bW0 = *reinterpret_cast<const short8*>(w0 + kkf * 16);
        short8 bW1 = *reinterpret_cast<const short8*>(w1 + kkf * 16);
        __builtin_amdgcn_s_setprio(1);
        y00 = __builtin_amdgcn_mfma_f32_32x32x16_bf16(aH0, bW0, y00, 0, 0, 0);
        y01 = __builtin_amdgcn_mfma_f32_32x32x16_bf16(aH1, bW0, y01, 0, 0, 0);
        y10 = __builtin_amdgcn_mfma_f32_32x32x16_bf16(aH0, bW1, y10, 0, 0, 0);
        y11 = __builtin_amdgcn_mfma_f32_32x32x16_bf16(aH1, bW1, y11, 0, 0, 0);
        __builtin_amdgcn_s_setprio(0);
      }
    };

#pragma unroll 1
    for (int j = 0; j < NCHUNK_TOT; ++j) {
      if (j > 0) consume(j - 1);
      bar_lgkm();   // BAR1: signal done reading Hf(j-1)
      bar_lgkm();   // BAR2: Hf(j) published
    }
    consume(NCHUNK_TOT - 1);   // drain (no barriers; G1 has exited)

    // ---- epilogue: out[t][c] = Y + wA*b2A + wB*b2B ----
#pragma unroll
    for (int ct = 0; ct < 2; ++ct) {
      int cc = wc * 64 + ct * 32 + l31;
      float bA = b2[e1 * NC + cc];
      float bB = b2[e2 * NC + cc];
#pragma unroll
      for (int tt = 0; tt < 2; ++tt) {
        const f32x16& Y = (ct == 0) ? ((tt == 0) ? y00 : y01)
                                    : ((tt == 0) ? y10 : y11);
#pragma unroll
        for (int q = 0; q < 4; ++q) {
          int pslot = tt * 2 + (q >> 1);
          if (pbase + pslot >= n) continue;
          int pid = pl[pslot];
          float wA = wvA[pslot], wB = wvB[pslot];
          int b = pid >> 10, pi = pid & 1023;
          int phi = pi >> 5, pwi = pi & 31;
          float bias = wA * bA + wB * bB;
#pragma unroll
          for (int i = 0; i < 4; ++i) {
            int tok = 8 * (q & 1) + 4 * lh + i;
            float* dst =
                out + (((size_t)(b * NH + phi * 4 + (tok >> 2)) * NW) + pwi * 4 + (tok & 3)) * NC;
            dst[cc] = Y[q * 4 + i] + bias;
          }
        }
      }
    }
  }
}

extern "C" void kernel_launch(void* const* d_in, const int* in_sizes, int n_in,
                              void* d_out, int out_size, void* d_ws, size_t ws_size,
                              hipStream_t stream) {
  const float* x  = (const float*)d_in[0];
  const float* Wg = (const float*)d_in[1];
  const float* W1 = (const float*)d_in[2];
  const float* b1 = (const float*)d_in[3];
  const float* W2 = (const float*)d_in[4];
  const float* b2 = (const float*)d_in[5];
  float* out = (float*)d_out;

  char* ws = (char*)d_ws;
  unsigned short* W1b = (unsigned short*)ws;                                  // 2 MiB
  unsigned short* W2b = (unsigned short*)(ws + (size_t)2 * 1024 * 1024);      // 2 MiB
  int*    cnt   = (int*)(ws + (size_t)4 * 1024 * 1024);                       // 64 B
  int*    plist = (int*)(ws + (size_t)4 * 1024 * 1024 + 256);                 // 256 KiB
  float2* wlist = (float2*)(ws + (size_t)4 * 1024 * 1024 + 256 +
                            (size_t)NPAIR * NPATCH * sizeof(int));            // 512 KiB
  int*    wl    = (int*)(ws + (size_t)5 * 1024 * 1024);                       // ~65 KiB

  convert_kernel<<<dim3(4096), dim3(256), 0, stream>>>(W1, W2, W1b, W2b, cnt, NE * NFF * NC);
  router_kernel<<<dim3(NPATCH), dim3(256), 0, stream>>>(x, Wg, cnt, plist, wlist);
  worklist_kernel<<<dim3(1), dim3(64), 0, stream>>>(cnt, wl);

  // padded slots: 8 * (max tiles in one class) <= 8 * (1024 + 1) = 8200
  ffn_kernel<<<dim3(8200), dim3(512), 0, stream>>>(
      x, b1, b2, W1b, W2b, cnt, plist, wlist, wl, out);
}

// Round 15
// 438.953 us; speedup vs baseline: 7.2403x; 7.2403x over previous
//
#include <hip/hip_runtime.h>
#include <hip/hip_bf16.h>
#include <cstdint>

// Problem constants (fixed by the reference)
#define NB 4
#define NH 128
#define NW 128
#define NC 256
#define NFF 1024
#define NE 4
#define NPATCH 4096   // B * 32 * 32
#define NPAIR 16      // ordered expert pairs (i1*4+i2), 12 valid
#define PPB 4         // patches per ffn block
#define BM 64         // token rows per ffn block (PPB*16)
#define FFC 128       // FF chunk
#define NCHUNK_TOT 16 // 2 experts x (NFF/FFC)

typedef __attribute__((ext_vector_type(8))) short short8;
typedef __attribute__((ext_vector_type(8))) unsigned short ushort8;
typedef __attribute__((ext_vector_type(16))) float f32x16;

__device__ __forceinline__ unsigned short f2b(float f) {
  union { float f; uint32_t u; } v; v.f = f;
  uint32_t u = v.u + 0x7FFFu + ((v.u >> 16) & 1u);   // RNE
  return (unsigned short)(u >> 16);
}

__device__ __forceinline__ float gelu_f(float v) {
  float u = v * v;
  float t = __builtin_fmaf(u, 0.044715f, 1.0f) * v;
  float e = __builtin_amdgcn_exp2f(t * -2.3022083f);
  return v * __builtin_amdgcn_rcpf(1.0f + e);
}

// barrier that drains LDS ops only (global loads stay in flight)
__device__ __forceinline__ void bar_lgkm() {
  asm volatile("s_waitcnt lgkmcnt(0)" ::: "memory");
  __builtin_amdgcn_s_barrier();
}

// ---------------- weight fp32 -> bf16 (+ cnt zeroing) ----------------
__global__ __launch_bounds__(256) void convert_kernel(
    const float* __restrict__ W1, const float* __restrict__ W2,
    unsigned short* __restrict__ W1b, unsigned short* __restrict__ W2b,
    int* __restrict__ cnt, int n) {
  int i = blockIdx.x * blockDim.x + threadIdx.x;
  if (i < NPAIR) cnt[i] = 0;
  if (i < n) {
    W1b[i] = f2b(W1[i]);
    W2b[i] = f2b(W2[i]);
  }
}

// ---------------- router ----------------
__global__ __launch_bounds__(256) void router_kernel(
    const float* __restrict__ x, const float* __restrict__ Wg,
    int* __restrict__ cnt, int* __restrict__ plist, float2* __restrict__ wlist) {
  int p = blockIdx.x;
  int b = p >> 10, pi = p & 1023;
  int phi = pi >> 5, pwi = pi & 31;
  int c = threadIdx.x;

  const float* base = x + (((size_t)(b * NH + phi * 4) * NW) + pwi * 4) * NC + c;
  float s = 0.f;
#pragma unroll
  for (int i = 0; i < 4; i++)
#pragma unroll
    for (int j = 0; j < 4; j++)
      s += base[(i * NW + j) * NC];
  float mean = s * (1.f / 16.f);

  __shared__ float m_lds[NC];
  __shared__ double logit_lds[NE];
  m_lds[c] = mean;
  __syncthreads();

  int wid = c >> 6, lane = c & 63;
  {
    const float* wg = Wg + wid * NC;
    double acc = 0.0;
#pragma unroll
    for (int q = 0; q < 4; q++)
      acc += (double)m_lds[lane + q * 64] * (double)wg[lane + q * 64];
    for (int off = 32; off; off >>= 1) acc += __shfl_down(acc, off);
    if (lane == 0) logit_lds[wid] = acc;
  }
  __syncthreads();

  if (c == 0) {
    double l[NE], pp[NE];
    double mx = -1e300;
#pragma unroll
    for (int i = 0; i < NE; i++) { l[i] = logit_lds[i]; mx = fmax(mx, l[i]); }
    double sum = 0.0;
#pragma unroll
    for (int i = 0; i < NE; i++) { pp[i] = exp(l[i] - mx); sum += pp[i]; }
#pragma unroll
    for (int i = 0; i < NE; i++) pp[i] /= sum;
    int i1 = 0; double p1 = pp[0];
    for (int i = 1; i < NE; i++) if (pp[i] > p1) { p1 = pp[i]; i1 = i; }
    int i2 = -1; double p2 = -1.0;
    for (int i = 0; i < NE; i++) {
      if (i == i1) continue;
      if (pp[i] > p2) { p2 = pp[i]; i2 = i; }
    }
    double den = p1 + p2 + 1e-9;
    float w1 = (float)(p1 / den), w2 = (float)(p2 / den);
    int pr = i1 * NE + i2;
    int pos = atomicAdd(&cnt[pr], 1);
    plist[pr * NPATCH + pos] = p;
    wlist[pr * NPATCH + pos] = make_float2(w1, w2);
  }
}

// ---------------- worklist: XCD-affine padded slots ----------------
__global__ __launch_bounds__(64) void worklist_kernel(
    const int* __restrict__ cnt, int* __restrict__ wl) {
  int lane = threadIdx.x;
  int cA[8], cB[8], mx = 0;
#pragma unroll
  for (int xc = 0; xc < 8; ++xc) {
    cA[xc] = (cnt[xc] + PPB - 1) / PPB;
    cB[xc] = (cnt[xc + 8] + PPB - 1) / PPB;
    int t = cA[xc] + cB[xc];
    mx = (t > mx) ? t : mx;
  }
  if (lane == 0) wl[0] = 8 * mx;
  int x = lane & 7, sub = lane >> 3;
  int nA = cA[x], tot = cA[x] + cB[x];
  for (int r = sub; r < mx; r += 8) {
    int ent = -1;
    if (r < nA) ent = (x << 12) | (r * PPB);
    else if (r < tot) ent = ((x + 8) << 12) | ((r - nA) * PPB);
    wl[1 + x + 8 * r] = ent;
  }
}

// ---------------- pair-FFN: lockstep 4 waves, 32x32 MFMA, frag-order LDS ----------------
// 256 thr / 4 waves, 48 KiB LDS -> 3 blocks/CU = 12 waves/CU (the TLP level
// that produced the best measured time, R3). Every wave, per 128-wide chunk:
// GEMM1 f-strip 32 (D[f][t], 2 t-tiles, acc1 = 2 f32x16) -> GELU +
// router-scale -> Hf fragment pages; then GEMM2 c-strip 64 (D[t][c],
// acc2 = 4 f32x16 persists over all 16 chunks). Weights load direct
// global->VGPR (L2-resident, XCD-affine) -- NO vmcnt fences anywhere
// (R13 showed they serialize); compiler pipelines the 32 weight loads per
// chunk freely. All MFMA operand LDS reads are lane-linear b128
// (conflict-free, verified 3M @R13). 2 lgkm-only barriers per chunk.
// launch_bounds(256,3): unified cap ~170 >= acc 96 + ~55 arch (R14 lesson:
// never cap below accumulator + working need).
__global__ __launch_bounds__(256, 3) void ffn_kernel(
    const float* __restrict__ x, const float* __restrict__ b1,
    const float* __restrict__ b2, const unsigned short* __restrict__ W1b,
    const unsigned short* __restrict__ W2b, const int* __restrict__ cnt,
    const int* __restrict__ plist, const float2* __restrict__ wlist,
    const int* __restrict__ wl, float* __restrict__ out) {
  __shared__ unsigned short Xf[2 * 16 * 512];   // 32 KiB: [tt][kk] frag pages
  __shared__ unsigned short Hf[2 * 8 * 512];    // 16 KiB: [tt][kkf] frag pages

  int slotb = blockIdx.x;
  if (slotb >= wl[0]) return;
  int ent = wl[1 + slotb];
  if (ent < 0) return;
  int pr = ent >> 12, pbase = ent & 4095;
  int e1 = pr >> 2, e2 = pr & 3;
  int n = cnt[pr];

  int tid = threadIdx.x, lane = tid & 63, wid = tid >> 6;
  int l31 = lane & 31, lh = lane >> 5;   // 32x32 frag: row/col = l31, k-half = lh

  const int*    pl  = plist + pr * NPATCH + pbase;
  const float2* wlp = wlist + pr * NPATCH + pbase;

  float wvA[PPB], wvB[PPB];
#pragma unroll
  for (int q = 0; q < PPB; q++) {
    if (pbase + q < n) { float2 w = wlp[q]; wvA[q] = w.x; wvB[q] = w.y; }
    else { wvA[q] = 0.f; wvB[q] = 0.f; }
  }

  // ---- gather tokens -> Xf fragment pages (256 threads, 64 ch each) ----
  {
    int r  = tid >> 2;            // 0..63 token row
    int c0 = (tid & 3) * 64;      // 64 channels per thread
    int pid = (pbase + (r >> 4) < n) ? pl[r >> 4] : -1;
    int t = r & 15;
    int tt = r >> 5, t32 = r & 31;
    if (pid >= 0) {
      int b = pid >> 10, pi = pid & 1023;
      int phi = pi >> 5, pwi = pi & 31;
      const float* src =
          x + (((size_t)(b * NH + phi * 4 + (t >> 2)) * NW) + pwi * 4 + (t & 3)) * NC + c0;
#pragma unroll
      for (int kb = 0; kb < 8; kb++) {
        float4 v0 = *reinterpret_cast<const float4*>(src + kb * 8);
        float4 v1 = *reinterpret_cast<const float4*>(src + kb * 8 + 4);
        ushort8 h;
        h[0] = f2b(v0.x); h[1] = f2b(v0.y); h[2] = f2b(v0.z); h[3] = f2b(v0.w);
        h[4] = f2b(v1.x); h[5] = f2b(v1.y); h[6] = f2b(v1.z); h[7] = f2b(v1.w);
        int k = c0 + kb * 8;
        int uidx = (tt * 16 + (k >> 4)) * 512 + (((k >> 3) & 1) * 32 + t32) * 8;
        *reinterpret_cast<ushort8*>(&Xf[uidx]) = h;
      }
    } else {
      ushort8 h = (ushort8)0;
#pragma unroll
      for (int kb = 0; kb < 8; kb++) {
        int k = c0 + kb * 8;
        int uidx = (tt * 16 + (k >> 4)) * 512 + (((k >> 3) & 1) * 32 + t32) * 8;
        *reinterpret_cast<ushort8*>(&Xf[uidx]) = h;
      }
    }
  }
  bar_lgkm();   // Xf visible

  const unsigned short* W1A = W1b + (size_t)e1 * NFF * NC;
  const unsigned short* W1B = W1b + (size_t)e2 * NFF * NC;
  const unsigned short* W2A = W2b + (size_t)e1 * NC * NFF;
  const unsigned short* W2B = W2b + (size_t)e2 * NC * NFF;
  const float* b1A = b1 + e1 * NFF;
  const float* b1B = b1 + e2 * NFF;

  int wf = wid;   // GEMM1 f-strip
  int wc = wid;   // GEMM2 c-strip

  f32x16 y00 = (f32x16)0.f, y01 = (f32x16)0.f;   // acc2: [c-tile][t-tile]
  f32x16 y10 = (f32x16)0.f, y11 = (f32x16)0.f;
  f32x16 a0, a1;                                  // acc1 (per chunk)
  ushort4 hreg[8];

#pragma unroll 1
  for (int j = 0; j < NCHUNK_TOT; ++j) {
    int fc = j & 7;
    const unsigned short* W1e = (j < 8) ? W1A : W1B;
    const float* b1e = (j < 8) ? b1A : b1B;
    a0 = (f32x16)0.f; a1 = (f32x16)0.f;

    // ---- GEMM1: D[f][t] += W1[f,k] * X[t,k] over K=256 ----
    const unsigned short* wrow = W1e + (size_t)(fc * FFC + wf * 32 + l31) * NC + lh * 8;
#pragma unroll
    for (int kf = 0; kf < 16; ++kf) {
      short8 aW = *reinterpret_cast<const short8*>(wrow + kf * 16);
      short8 bX0 = *reinterpret_cast<const short8*>(&Xf[(0 * 16 + kf) * 512 + lane * 8]);
      short8 bX1 = *reinterpret_cast<const short8*>(&Xf[(1 * 16 + kf) * 512 + lane * 8]);
      a0 = __builtin_amdgcn_mfma_f32_32x32x16_bf16(aW, bX0, a0, 0, 0, 0);
      a1 = __builtin_amdgcn_mfma_f32_32x32x16_bf16(aW, bX1, a1, 0, 0, 0);
    }

    // ---- GELU + router-scale -> hreg (D[f][t]: t = l31, patch by l31>>4) ----
#pragma unroll
    for (int tt = 0; tt < 2; ++tt) {
      const f32x16& A = (tt == 0) ? a0 : a1;
      float wlo = (j < 8) ? wvA[tt * 2]     : wvB[tt * 2];
      float whi = (j < 8) ? wvA[tt * 2 + 1] : wvB[tt * 2 + 1];
      float w = (l31 >= 16) ? whi : wlo;
#pragma unroll
      for (int q = 0; q < 4; ++q) {
        int qs = q * 8 + lh * 4;                  // f-local base of this reg-quad
        float4 bv = *reinterpret_cast<const float4*>(b1e + fc * FFC + wf * 32 + qs);
        ushort4 hp;
        hp.x = f2b(gelu_f(A[q * 4 + 0] + bv.x) * w);
        hp.y = f2b(gelu_f(A[q * 4 + 1] + bv.y) * w);
        hp.z = f2b(gelu_f(A[q * 4 + 2] + bv.z) * w);
        hp.w = f2b(gelu_f(A[q * 4 + 3] + bv.w) * w);
        hreg[tt * 4 + q] = hp;
      }
    }

    bar_lgkm();   // BAR1: all waves finished GEMM2(j-1) reads of Hf
#pragma unroll
    for (int tt = 0; tt < 2; ++tt) {
#pragma unroll
      for (int q = 0; q < 4; ++q) {
        int qs = q * 8 + lh * 4;
        int page = tt * 8 + wf * 2 + (qs >> 4);
        int uidx = page * 512 + (((qs >> 3) & 1) * 32 + l31) * 8 + (qs & 4);
        *reinterpret_cast<ushort4*>(&Hf[uidx]) = hreg[tt * 4 + q];
      }
    }
    bar_lgkm();   // BAR2: Hf(j) published

    // ---- GEMM2: D[t][c] += H[t,f] * W2[c,f] over FFC=128 ----
    const unsigned short* W2e = (j < 8) ? W2A : W2B;
    const unsigned short* w0 = W2e + (size_t)(wc * 64 + l31) * NFF + fc * FFC + lh * 8;
    const unsigned short* w1 = W2e + (size_t)(wc * 64 + 32 + l31) * NFF + fc * FFC + lh * 8;
#pragma unroll
    for (int kkf = 0; kkf < 8; ++kkf) {
      short8 aH0 = *reinterpret_cast<const short8*>(&Hf[(0 * 8 + kkf) * 512 + lane * 8]);
      short8 aH1 = *reinterpret_cast<const short8*>(&Hf[(1 * 8 + kkf) * 512 + lane * 8]);
      short8 bW0 = *reinterpret_cast<const short8*>(w0 + kkf * 16);
      short8 bW1 = *reinterpret_cast<const short8*>(w1 + kkf * 16);
      y00 = __builtin_amdgcn_mfma_f32_32x32x16_bf16(aH0, bW0, y00, 0, 0, 0);
      y01 = __builtin_amdgcn_mfma_f32_32x32x16_bf16(aH1, bW0, y01, 0, 0, 0);
      y10 = __builtin_amdgcn_mfma_f32_32x32x16_bf16(aH0, bW1, y10, 0, 0, 0);
      y11 = __builtin_amdgcn_mfma_f32_32x32x16_bf16(aH1, bW1, y11, 0, 0, 0);
    }
  }

  // ---- epilogue: out[t][c] = Y + wA*b2A + wB*b2B ----
#pragma unroll
  for (int ct = 0; ct < 2; ++ct) {
    int cc = wc * 64 + ct * 32 + l31;
    float bA = b2[e1 * NC + cc];
    float bB = b2[e2 * NC + cc];
#pragma unroll
    for (int tt = 0; tt < 2; ++tt) {
      const f32x16& Y = (ct == 0) ? ((tt == 0) ? y00 : y01)
                                  : ((tt == 0) ? y10 : y11);
#pragma unroll
      for (int q = 0; q < 4; ++q) {
        int pslot = tt * 2 + (q >> 1);
        if (pbase + pslot >= n) continue;
        int pid = pl[pslot];
        float wA = wvA[pslot], wB = wvB[pslot];
        int b = pid >> 10, pi = pid & 1023;
        int phi = pi >> 5, pwi = pi & 31;
        float bias = wA * bA + wB * bB;
#pragma unroll
        for (int i = 0; i < 4; ++i) {
          int tok = 8 * (q & 1) + 4 * lh + i;
          float* dst =
              out + (((size_t)(b * NH + phi * 4 + (tok >> 2)) * NW) + pwi * 4 + (tok & 3)) * NC;
          dst[cc] = Y[q * 4 + i] + bias;
        }
      }
    }
  }
}

extern "C" void kernel_launch(void* const* d_in, const int* in_sizes, int n_in,
                              void* d_out, int out_size, void* d_ws, size_t ws_size,
                              hipStream_t stream) {
  const float* x  = (const float*)d_in[0];
  const float* Wg = (const float*)d_in[1];
  const float* W1 = (const float*)d_in[2];
  const float* b1 = (const float*)d_in[3];
  const float* W2 = (const float*)d_in[4];
  const float* b2 = (const float*)d_in[5];
  float* out = (float*)d_out;

  char* ws = (char*)d_ws;
  unsigned short* W1b = (unsigned short*)ws;                                  // 2 MiB
  unsigned short* W2b = (unsigned short*)(ws + (size_t)2 * 1024 * 1024);      // 2 MiB
  int*    cnt   = (int*)(ws + (size_t)4 * 1024 * 1024);                       // 64 B
  int*    plist = (int*)(ws + (size_t)4 * 1024 * 1024 + 256);                 // 256 KiB
  float2* wlist = (float2*)(ws + (size_t)4 * 1024 * 1024 + 256 +
                            (size_t)NPAIR * NPATCH * sizeof(int));            // 512 KiB
  int*    wl    = (int*)(ws + (size_t)5 * 1024 * 1024);                       // ~33 KiB

  convert_kernel<<<dim3(4096), dim3(256), 0, stream>>>(W1, W2, W1b, W2b, cnt, NE * NFF * NC);
  router_kernel<<<dim3(NPATCH), dim3(256), 0, stream>>>(x, Wg, cnt, plist, wlist);
  worklist_kernel<<<dim3(1), dim3(64), 0, stream>>>(cnt, wl);

  // padded slots: 8 * (max tiles in one class) <= 8 * (1024 + 1) = 8200
  ffn_kernel<<<dim3(8200), dim3(256), 0, stream>>>(
      x, b1, b2, W1b, W2b, cnt, plist, wlist, wl, out);
}